// Round 8
// baseline (287.251 us; speedup 1.0000x reference)
//
#include <hip/hip_runtime.h>

#define Hh 64
#define Ww 64
#define Cc 512
#define Bb 16
#define NTOK (1 + Hh * Ww)   // 4097
#define TW 8                 // output pixels per thread along w
#define TH 2                 // output pixels per thread along h

typedef float v2f __attribute__((ext_vector_type(2)));

// ---------------------------------------------------------------------------
// Prep kernel (unchanged): combine w7 + padded w5 + padded w3 + identity into
// one effective 7x7 kernel per channel, stored TRANSPOSED [tap][channel].
// Combine biases, copy cls tokens through.
// ---------------------------------------------------------------------------
__global__ void ppeg_prep(const float* __restrict__ w7, const float* __restrict__ b7,
                          const float* __restrict__ w5, const float* __restrict__ b5,
                          const float* __restrict__ w3, const float* __restrict__ b3,
                          const float* __restrict__ x, float* __restrict__ wt,
                          float* __restrict__ beff, float* __restrict__ out) {
    int idx = blockIdx.x * blockDim.x + threadIdx.x;
    if (idx < Cc * 49) {
        int c = idx / 49, t = idx % 49;
        int r = t / 7, s = t % 7;
        float v = w7[idx];
        if (r >= 1 && r <= 5 && s >= 1 && s <= 5) v += w5[c * 25 + (r - 1) * 5 + (s - 1)];
        if (r >= 2 && r <= 4 && s >= 2 && s <= 4) v += w3[c * 9 + (r - 2) * 3 + (s - 2)];
        if (t == 24) v += 1.0f;               // identity (center tap)
        wt[t * Cc + c] = v;                   // transposed store
    }
    if (idx < Cc) beff[idx] = b7[idx] + b5[idx] + b3[idx];
    if (idx < Bb * Cc) {
        int b = idx / Cc, c = idx % Cc;
        size_t o = (size_t)b * NTOK * Cc + c;
        out[o] = x[o];                        // cls token pass-through
    }
}

// ---------------------------------------------------------------------------
// Conv kernel v9: back to the v6 structure (register windows, direct global
// loads — the LDS-staging arc v7/v8 regressed: it added ~400 cy/row of
// ds_read to data that was already L2-resident), with the per-thread tile
// shrunk TH 4->2 so the DOUBLE-BUFFERED window actually fits the register
// budget the allocator grants.
//
// v6 diagnosis (104 us, VALU 26%): acc[64]+window[28] vs a 64-arch-VGPR
// allocation -> overflow parked in AGPRs, no headroom to hoist row k+1's
// loads over row k's FMAs -> per-row burst-drain, ~75% stall. R2/R3: the
// budget can't be raised by attributes. v7/v8: LDS can't substitute.
// v9: live set ~105 regs (acc 32 + vbuf 2x14x2 = 56 + addressing) fits the
// 96-128 regs that 256-thread blocks get (R1 precedent: live ~110 -> 96
// regs, zero spills). Explicit vbuf[2][14] double-buffer, all indices
// static after full unroll: row k+1's 14 dwordx2 loads issue BEFORE row
// k's ~390 cy of FMA -> the ~220 cy L2-hit latency (everything is L2-hot
// after the XCD swizzle) is fully hidden within each wave.
//
// Kept (proven): float2 channel lanes (512 B/wave-load), LDS tap slab
// (25 KB, bank-conflict-free), chunked XCD swizzle (FETCH at the 134 MB
// compulsory minimum), nontemporal stores, 256-thread blocks.
// Occupancy: LDS caps at 6 blocks/CU; VGPR caps at 4-5 waves/SIMD ->
// expect ~16-20 waves/CU (45-60%), ~2x v6.
// ---------------------------------------------------------------------------
__global__ __launch_bounds__(256, 2)
void ppeg_conv(const float* __restrict__ x, const float* __restrict__ wt,
               const float* __restrict__ beff, float* __restrict__ out) {
    const int tx = threadIdx.x;        // channel-pair lane 0..63
    const int ty = threadIdx.y;        // h-strip 0..3 (wave-uniform)

    // --- chunked XCD swizzle (XCD = linear id % 8, x fastest; 4096%8==0) ----
    const int L     = blockIdx.x + 64 * (blockIdx.y + 4 * blockIdx.z); // 0..4095
    const int g_lin = (L & 7) * 512 + (L >> 3);
    const int sp    = g_lin & 63;      // spatial block 0..63 within group
    const int g     = g_lin >> 6;      // 0..63 : (cblk, b) group
    const int cb    = (g & 3) * 128;
    const int b     = g >> 2;
    // ------------------------------------------------------------------------

    const int wblk  = sp & 7;
    const int hblk  = sp >> 3;         // 0..7
    const int oh0   = hblk * (TH * 4) + ty * TH;   // first of TH output rows
    const int wbase = wblk * TW;

    // Stage the block's 49x128 tap slab into LDS (once), coalesced.
    __shared__ float taps[49][128];
    const int tid = ty * 64 + tx;
    for (int idx = tid; idx < 49 * 128; idx += 256) {
        taps[idx >> 7][idx & 127] = wt[(idx >> 7) * Cc + cb + (idx & 127)];
    }
    __syncthreads();

    const int c0 = cb + 2 * tx;
    const float* xb = x + ((size_t)b * NTOK + 1) * Cc + c0;  // pixel (0,0)

    const v2f bias = *(const v2f*)&beff[c0];
    v2f acc[TH][TW];
#pragma unroll
    for (int o = 0; o < TH; ++o)
#pragma unroll
        for (int j = 0; j < TW; ++j) acc[o][j] = bias;

    const bool interior = (wblk != 0) && (wblk != 7);

    v2f vbuf[2][TW + 6];               // double-buffered input row window

    auto loadrow = [&](v2f* __restrict__ v, int k) {
        const int ir = oh0 + k - 3;
        if (ir < 0 || ir >= Hh) return;            // wave-uniform
        const float* xrow = xb + (size_t)ir * (Ww * Cc);
        if (interior) {
#pragma unroll
            for (int j = 0; j < TW + 6; ++j)
                v[j] = *(const v2f*)(xrow + (size_t)(wbase - 3 + j) * Cc);
        } else {
#pragma unroll
            for (int j = 0; j < TW + 6; ++j) {
                const int wc = wbase + j - 3;      // lane-uniform condition
                if (wc >= 0 && wc < Ww)
                    v[j] = *(const v2f*)(xrow + (size_t)wc * Cc);
                else { v[j].x = 0.0f; v[j].y = 0.0f; }
            }
        }
    };

    loadrow(vbuf[0], 0);               // prologue: row 0 in flight

    // Stream the strip's TH+6 = 8 input rows. Row k feeds output rows
    // o in [k-6, k]. Full unroll -> vbuf indices (k&1) are static.
#pragma unroll
    for (int k = 0; k < TH + 6; ++k) {
        if (k + 1 < TH + 6) loadrow(vbuf[(k + 1) & 1], k + 1);   // prefetch
        const int ir = oh0 + k - 3;
        if (ir >= 0 && ir < Hh) {                   // wave-uniform
            const v2f* v = vbuf[k & 1];
#pragma unroll
            for (int o = 0; o < TH; ++o) {
                if (o > k || o < k - 6) continue;   // static after unroll
                const int r = k - o;
#pragma unroll
                for (int s = 0; s < 7; ++s) {
                    const v2f tp = *(const v2f*)&taps[r * 7 + s][2 * tx];
#pragma unroll
                    for (int j = 0; j < TW; ++j) {
                        acc[o][j].x = fmaf(tp.x, v[j + s].x, acc[o][j].x);
                        acc[o][j].y = fmaf(tp.y, v[j + s].y, acc[o][j].y);
                    }
                }
            }
        }
    }

#pragma unroll
    for (int o = 0; o < TH; ++o) {
        float* orow = out + ((size_t)b * NTOK + 1 + (size_t)(oh0 + o) * Ww + wbase) * Cc + c0;
#pragma unroll
        for (int j = 0; j < TW; ++j)
            __builtin_nontemporal_store(acc[o][j], (v2f*)(orow + (size_t)j * Cc));
    }
}

extern "C" void kernel_launch(void* const* d_in, const int* in_sizes, int n_in,
                              void* d_out, int out_size, void* d_ws, size_t ws_size,
                              hipStream_t stream) {
    const float* x  = (const float*)d_in[0];
    const float* w7 = (const float*)d_in[1];
    const float* b7 = (const float*)d_in[2];
    const float* w5 = (const float*)d_in[3];
    const float* b5 = (const float*)d_in[4];
    const float* w3 = (const float*)d_in[5];
    const float* b3 = (const float*)d_in[6];
    float* out = (float*)d_out;

    float* wt   = (float*)d_ws;          // 49*Cc floats, transposed [tap][channel]
    float* beff = wt + 49 * Cc;          // Cc floats

    ppeg_prep<<<(Cc * 49 + 255) / 256, 256, 0, stream>>>(w7, b7, w5, b5, w3, b3,
                                                         x, wt, beff, out);

    // (8 hblk x 8 wblk) x 4 cblk x 16 b = 4096 blocks of 256 threads.
    dim3 grid(64, Cc / 128, Bb);
    dim3 block(64, 4);
    ppeg_conv<<<grid, block, 0, stream>>>(x, wt, beff, out);
}

// Round 9
// 270.577 us; speedup vs baseline: 1.0616x; 1.0616x over previous
//
#include <hip/hip_runtime.h>

#define Hh 64
#define Ww 64
#define Cc 512
#define Bb 16
#define NTOK (1 + Hh * Ww)   // 4097
#define TW 8                 // output pixels per thread along w
#define TH 4                 // output pixels per thread along h

typedef float v2f __attribute__((ext_vector_type(2)));

// ---------------------------------------------------------------------------
// Prep kernel (unchanged): combine w7 + padded w5 + padded w3 + identity into
// one effective 7x7 kernel per channel, stored TRANSPOSED [tap][channel].
// Combine biases, copy cls tokens through.
// ---------------------------------------------------------------------------
__global__ void ppeg_prep(const float* __restrict__ w7, const float* __restrict__ b7,
                          const float* __restrict__ w5, const float* __restrict__ b5,
                          const float* __restrict__ w3, const float* __restrict__ b3,
                          const float* __restrict__ x, float* __restrict__ wt,
                          float* __restrict__ beff, float* __restrict__ out) {
    int idx = blockIdx.x * blockDim.x + threadIdx.x;
    if (idx < Cc * 49) {
        int c = idx / 49, t = idx % 49;
        int r = t / 7, s = t % 7;
        float v = w7[idx];
        if (r >= 1 && r <= 5 && s >= 1 && s <= 5) v += w5[c * 25 + (r - 1) * 5 + (s - 1)];
        if (r >= 2 && r <= 4 && s >= 2 && s <= 4) v += w3[c * 9 + (r - 2) * 3 + (s - 2)];
        if (t == 24) v += 1.0f;               // identity (center tap)
        wt[t * Cc + c] = v;                   // transposed store
    }
    if (idx < Cc) beff[idx] = b7[idx] + b5[idx] + b3[idx];
    if (idx < Bb * Cc) {
        int b = idx / Cc, c = idx % Cc;
        size_t o = (size_t)b * NTOK * Cc + c;
        out[o] = x[o];                        // cls token pass-through
    }
}

// ---------------------------------------------------------------------------
// Conv kernel v10 = v6 (the best-known config: TH=4 register windows, float2
// channel lanes, LDS tap slab, chunked XCD swizzle, nontemporal stores)
// with ONE change: the inner FMA is written as VECTOR arithmetic under
// fp contract(fast) so the compiler emits v_pk_fma_f32 (packed 2xfp32,
// gfx90a+) instead of the 2x scalar v_fma_f32 that component-wise fmaf()
// forced. Halves the dominant VALU instruction stream (3136 -> 1568
// instrs/thread; 6272 -> 3136 issue-cycles/wave).
//
// Purpose: the discriminating A/B after 5 flat structural rounds. Every
// structure lands at VALUBusy 25-28% (occ 16%..73%, regs vs LDS staging,
// syncthreads vs counted vmcnt). If v10's time is unchanged while VALUBusy
// halves -> pure latency-bound confirmed, issue-side work is done. If time
// drops to ~85-95 us -> the instruction stream was part of the stall
// (issue-mix contention), and further vectorization (v4f lanes) is next.
//
// History: v6=104us (best). v7/v8 LDS-staging arc=126 (staging L2-resident
// data is pure overhead, Common-mistake #7). v9 TH=2 dbuf=123 (smaller tile
// pays 1.6x read redundancy; VGPR pinned at 64 regardless of live set).
// ---------------------------------------------------------------------------
__global__ __launch_bounds__(256, 2)
void ppeg_conv(const float* __restrict__ x, const float* __restrict__ wt,
               const float* __restrict__ beff, float* __restrict__ out) {
#pragma clang fp contract(fast)
    const int tx = threadIdx.x;        // channel-pair lane 0..63
    const int ty = threadIdx.y;        // h-strip 0..3 (wave-uniform)

    // --- chunked XCD swizzle (XCD = linear id % 8, x fastest; bijective) ----
    const int L     = blockIdx.x + 32 * (blockIdx.y + 4 * blockIdx.z); // 0..2047
    const int g_lin = (L & 7) * 256 + (L >> 3);
    const int sp    = g_lin & 31;      // spatial block 0..31 within group
    const int g     = g_lin >> 5;      // 0..63 : (cblk, b) group
    const int cb    = (g & 3) * 128;
    const int b     = g >> 2;
    // ------------------------------------------------------------------------

    const int wblk  = sp & 7;
    const int hblk  = sp >> 3;
    const int oh0   = hblk * (TH * 4) + ty * TH;   // first of TH output rows
    const int wbase = wblk * TW;

    // Stage the block's 49x128 tap slab into LDS (once), coalesced.
    __shared__ float taps[49][128];
    const int tid = ty * 64 + tx;
    for (int idx = tid; idx < 49 * 128; idx += 256) {
        taps[idx >> 7][idx & 127] = wt[(idx >> 7) * Cc + cb + (idx & 127)];
    }
    __syncthreads();

    const int c0 = cb + 2 * tx;
    const float* xb = x + ((size_t)b * NTOK + 1) * Cc + c0;  // pixel (0,0)

    const v2f bias = *(const v2f*)&beff[c0];
    v2f acc[TH][TW];
#pragma unroll
    for (int o = 0; o < TH; ++o)
#pragma unroll
        for (int j = 0; j < TW; ++j) acc[o][j] = bias;

    const bool interior = (wblk != 0) && (wblk != 7);

    // Stream input rows ir = oh0-3 .. oh0+TH+2. Row k feeds output rows
    // o in [k-6, k] (tap row r = k-o). All indices static after unroll.
#pragma unroll
    for (int k = 0; k < TH + 6; ++k) {
        const int ir = oh0 + k - 3;
        if (ir >= 0 && ir < Hh) {              // wave-uniform (oh0 fixed/wave)
            const float* xrow = xb + (size_t)ir * (Ww * Cc);
            v2f v[TW + 6];
            if (interior) {
#pragma unroll
                for (int j = 0; j < TW + 6; ++j)
                    v[j] = *(const v2f*)(xrow + (size_t)(wbase - 3 + j) * Cc);
            } else {
#pragma unroll
                for (int j = 0; j < TW + 6; ++j) {
                    const int wc = wbase + j - 3;
                    if (wc >= 0 && wc < Ww)
                        v[j] = *(const v2f*)(xrow + (size_t)wc * Cc);
                    else {
                        v[j].x = 0.0f; v[j].y = 0.0f;
                    }
                }
            }
#pragma unroll
            for (int o = 0; o < TH; ++o) {
                if (o > k || o < k - 6) continue;   // static after unroll
                const int r = k - o;
#pragma unroll
                for (int s = 0; s < 7; ++s) {
                    const v2f tp = *(const v2f*)&taps[r * 7 + s][2 * tx];
#pragma unroll
                    for (int j = 0; j < TW; ++j)
                        acc[o][j] = tp * v[j + s] + acc[o][j];   // -> v_pk_fma_f32
                }
            }
        }
    }

#pragma unroll
    for (int o = 0; o < TH; ++o) {
        float* orow = out + ((size_t)b * NTOK + 1 + (size_t)(oh0 + o) * Ww + wbase) * Cc + c0;
#pragma unroll
        for (int j = 0; j < TW; ++j)
            __builtin_nontemporal_store(acc[o][j], (v2f*)(orow + (size_t)j * Cc));
    }
}

extern "C" void kernel_launch(void* const* d_in, const int* in_sizes, int n_in,
                              void* d_out, int out_size, void* d_ws, size_t ws_size,
                              hipStream_t stream) {
    const float* x  = (const float*)d_in[0];
    const float* w7 = (const float*)d_in[1];
    const float* b7 = (const float*)d_in[2];
    const float* w5 = (const float*)d_in[3];
    const float* b5 = (const float*)d_in[4];
    const float* w3 = (const float*)d_in[5];
    const float* b3 = (const float*)d_in[6];
    float* out = (float*)d_out;

    float* wt   = (float*)d_ws;          // 49*Cc floats, transposed [tap][channel]
    float* beff = wt + 49 * Cc;          // Cc floats

    ppeg_prep<<<(Cc * 49 + 255) / 256, 256, 0, stream>>>(w7, b7, w5, b5, w3, b3,
                                                         x, wt, beff, out);

    // (4 hblk x 8 wblk) x 4 cblk x 16 b = 2048 blocks of 256 threads.
    dim3 grid(32, Cc / 128, Bb);
    dim3 block(64, 4);
    ppeg_conv<<<grid, block, 0, stream>>>(x, wt, beff, out);
}